// Round 13
// baseline (882.804 us; speedup 1.0000x reference)
//
#include <hip/hip_runtime.h>
#include <math.h>
#include <stdint.h>

#define B_V 48
#define B_T 48
#define MQ 32
#define NN 196
#define CC 512
#define HID 102
#define KEEPN 39
#define NKEEP 98
#define TOKS 41

__device__ __forceinline__ float waveSum(float v) {
#pragma unroll
  for (int off = 32; off > 0; off >>= 1) v += __shfl_xor(v, off, 64);
  return v;
}
__device__ __forceinline__ float waveMax(float v) {
#pragma unroll
  for (int off = 32; off > 0; off >>= 1) v = fmaxf(v, __shfl_xor(v, off, 64));
  return v;
}

// ---------------- prep per image: glo, s_im, ninv, clsInv -----------------
__global__ __launch_bounds__(256) void k_prep_img(const float* __restrict__ img,
                                                  float* __restrict__ ninv,
                                                  float* __restrict__ s_im,
                                                  float* __restrict__ clsInvG) {
  int b = blockIdx.x, t = threadIdx.x;
  __shared__ float glo[CC];
  __shared__ float red[256];
  __shared__ float rgS;
  const float* sp = img + ((size_t)b * 197 + 1) * CC;
  float v0 = 0.f, v1 = 0.f;
  for (int n = 0; n < NN; ++n) {
    v0 += sp[(size_t)n * CC + t];
    v1 += sp[(size_t)n * CC + t + 256];
  }
  v0 *= (1.f / NN); v1 *= (1.f / NN);
  glo[t] = v0; glo[t + 256] = v1;
  red[t] = v0 * v0 + v1 * v1;
  __syncthreads();
  for (int s = 128; s > 0; s >>= 1) {
    if (t < s) red[t] += red[t + s];
    __syncthreads();
  }
  if (t == 0) rgS = 1.f / fmaxf(sqrtf(red[0]), 1e-12f);
  __syncthreads();
  float rg = rgS;
  glo[t] *= rg; glo[t + 256] *= rg;
  __syncthreads();
  int w = t >> 6, lane = t & 63;
  for (int n = w; n < NN; n += 4) {
    const float* row = sp + (size_t)n * CC + lane * 8;
    float4 a = *(const float4*)row;
    float4 bq = *(const float4*)(row + 4);
    const float* gl = glo + lane * 8;
    float ss = a.x * a.x + a.y * a.y + a.z * a.z + a.w * a.w +
               bq.x * bq.x + bq.y * bq.y + bq.z * bq.z + bq.w * bq.w;
    float dt = a.x * gl[0] + a.y * gl[1] + a.z * gl[2] + a.w * gl[3] +
               bq.x * gl[4] + bq.y * gl[5] + bq.z * gl[6] + bq.w * gl[7];
    ss = waveSum(ss);
    dt = waveSum(dt);
    if (lane == 0) {
      float nv = 1.f / fmaxf(sqrtf(ss), 1e-12f);
      ninv[b * NN + n] = nv;
      s_im[b * NN + n] = dt * nv;
    }
  }
  __syncthreads();
  {  // cls norm (j-independent hoist)
    const float* cls = img + (size_t)b * 197 * CC;
    float c0v = cls[t], c1v = cls[t + 256];
    red[t] = c0v * c0v + c1v * c1v;
    __syncthreads();
    for (int s = 128; s > 0; s >>= 1) {
      if (t < s) red[t] += red[t + s];
      __syncthreads();
    }
    if (t == 0) clsInvG[b] = 1.f / fmaxf(sqrtf(red[0]), 1e-12f);
  }
}

// ---------------- prep per caption: inverse norms -------------------------
__global__ __launch_bounds__(256) void k_prep_cap(const float* __restrict__ cap,
                                                  float* __restrict__ cinv) {
  int j = blockIdx.x, t = threadIdx.x, w = t >> 6, lane = t & 63;
  for (int m = w; m < MQ; m += 4) {
    const float* row = cap + ((size_t)j * MQ + m) * CC + lane * 8;
    float4 a = *(const float4*)row;
    float4 bq = *(const float4*)(row + 4);
    float ss = a.x * a.x + a.y * a.y + a.z * a.z + a.w * a.w +
               bq.x * bq.x + bq.y * bq.y + bq.z * bq.z + bq.w * bq.w;
    ss = waveSum(ss);
    if (lane == 0) cinv[j * MQ + m] = 1.f / fmaxf(sqrtf(ss), 1e-12f);
  }
}

// ---------------- fold LN into w1 ----------------
__global__ __launch_bounds__(256) void k_fold(const float* __restrict__ w1,
                                              const float* __restrict__ b1,
                                              const float* __restrict__ ln_g,
                                              const float* __restrict__ ln_b,
                                              float* __restrict__ w1gT,
                                              float* __restrict__ A,
                                              float* __restrict__ Bc) {
  int j = blockIdx.x, t = threadIdx.x;
  __shared__ float r1[4], r2[4];
  float v0 = 0.f, v1 = 0.f, ba = 0.f;
  if (j < HID) {
    float wv0 = w1[(size_t)t * HID + j];
    float wv1 = w1[(size_t)(t + 256) * HID + j];
    v0 = ln_g[t] * wv0;
    v1 = ln_g[t + 256] * wv1;
    ba = ln_b[t] * wv0 + ln_b[t + 256] * wv1;
  }
  w1gT[(size_t)j * 512 + t] = v0;
  w1gT[(size_t)j * 512 + t + 256] = v1;
  float aa = waveSum(v0 + v1);
  float bb = waveSum(ba);
  int wv = t >> 6, lane = t & 63;
  if (lane == 0) { r1[wv] = aa; r2[wv] = bb; }
  __syncthreads();
  if (t == 0) {
    float sa = r1[0] + r1[1] + r1[2] + r1[3];
    float sb = r2[0] + r2[1] + r2[2] + r2[3];
    A[j] = (j < HID) ? sa : 0.f;
    Bc[j] = (j < HID) ? (sb + b1[j]) : 0.f;
  }
}

// ---------------- per-token LN stats ----------------
__global__ __launch_bounds__(256) void k_ln(const float* __restrict__ img,
                                            float* __restrict__ muG,
                                            float* __restrict__ rsG) {
  int t = threadIdx.x, wv = t >> 6, lane = t & 63;
  int tokG = blockIdx.x * 4 + wv;
  int b = tokG / NN, n = tokG - b * NN;
  const float* row = img + ((size_t)b * 197 + 1 + n) * CC + lane * 8;
  float4 a = *(const float4*)row;
  float4 bq = *(const float4*)(row + 4);
  float sm = a.x + a.y + a.z + a.w + bq.x + bq.y + bq.z + bq.w;
  float ss = a.x * a.x + a.y * a.y + a.z * a.z + a.w * a.w +
             bq.x * bq.x + bq.y * bq.y + bq.z * bq.z + bq.w * bq.w;
  sm = waveSum(sm);
  ss = waveSum(ss);
  if (lane == 0) {
    float mu = sm * (1.f / CC);
    float var = ss * (1.f / CC) - mu * mu;
    muG[tokG] = mu;
    rsG[tokG] = rsqrtf(var + 1e-5f);
  }
}

// ---------------- s_load helpers ----------------
typedef __attribute__((ext_vector_type(8))) float f32x8;
typedef __attribute__((ext_vector_type(16))) float f32x16;

#define SL8(dst, off_lit) \
  asm volatile("s_load_dwordx8 %0, %1, " off_lit : "=s"(dst) : "s"(bp))

#define SL16(dst, off_lit) \
  asm volatile("s_load_dwordx16 %0, %1, " off_lit : "=s"(dst) : "s"(bp))

#define SWAIT8() \
  asm volatile("s_waitcnt lgkmcnt(0)" \
               : "+s"(s0), "+s"(s1), "+s"(s2), "+s"(s3), \
                 "+s"(s4), "+s"(s5), "+s"(s6), "+s"(s7))

#define SWAIT5() \
  asm volatile("s_waitcnt lgkmcnt(0)" \
               : "+s"(s0), "+s"(s1), "+s"(s2), "+s"(s3), "+s"(s4))

#define SWAITQ() \
  asm volatile("s_waitcnt lgkmcnt(0)" : "+s"(q0), "+s"(q1), "+s"(q2), "+s"(q3))

#define DOT8(S, I) do { float t_ = acc[I]; \
  t_ = fmaf(S[0], a[0], t_); t_ = fmaf(S[1], a[1], t_); \
  t_ = fmaf(S[2], a[2], t_); t_ = fmaf(S[3], a[3], t_); \
  t_ = fmaf(S[4], a[4], t_); t_ = fmaf(S[5], a[5], t_); \
  t_ = fmaf(S[6], a[6], t_); t_ = fmaf(S[7], a[7], t_); \
  acc[I] = t_; } while (0)

// DOT16 against an arbitrary accumulator array and a-chunk.
#define DOT16A(S, ACC, I, A_) do { float t_ = ACC[I]; \
  t_ = fmaf(S[0], A_[0], t_);   t_ = fmaf(S[1], A_[1], t_); \
  t_ = fmaf(S[2], A_[2], t_);   t_ = fmaf(S[3], A_[3], t_); \
  t_ = fmaf(S[4], A_[4], t_);   t_ = fmaf(S[5], A_[5], t_); \
  t_ = fmaf(S[6], A_[6], t_);   t_ = fmaf(S[7], A_[7], t_); \
  t_ = fmaf(S[8], A_[8], t_);   t_ = fmaf(S[9], A_[9], t_); \
  t_ = fmaf(S[10], A_[10], t_); t_ = fmaf(S[11], A_[11], t_); \
  t_ = fmaf(S[12], A_[12], t_); t_ = fmaf(S[13], A_[13], t_); \
  t_ = fmaf(S[14], A_[14], t_); t_ = fmaf(S[15], A_[15], t_); \
  ACC[I] = t_; } while (0)

// Empty volatile asm: pins loaded floats into registers exactly once.
#define PIN16(a0, a1, a2, a3) \
  asm volatile("" : "+v"(a0.x), "+v"(a0.y), "+v"(a0.z), "+v"(a0.w), \
                    "+v"(a1.x), "+v"(a1.y), "+v"(a1.z), "+v"(a1.w), \
                    "+v"(a2.x), "+v"(a2.y), "+v"(a2.z), "+v"(a2.w), \
                    "+v"(a3.x), "+v"(a3.y), "+v"(a3.z), "+v"(a3.w))

// ---------------- fused x@w1g (+gelu) @ w2 per 64-token tile --------------
__global__ __launch_bounds__(512, 2) void k_gemm(const float* __restrict__ img,
                                                 const float* __restrict__ w1gT,
                                                 const float* __restrict__ A,
                                                 const float* __restrict__ Bc,
                                                 const float* __restrict__ muG,
                                                 const float* __restrict__ rsG,
                                                 const float* __restrict__ w2,
                                                 const float* __restrict__ b2,
                                                 float* __restrict__ y) {
  __shared__ float hL[64 * 105];
  __shared__ float w2L[HID * 40];
  int t = threadIdx.x;
  int tok = t & 63, wv = t >> 6;
  int tokG = blockIdx.x * 64 + tok;
  int b = tokG / NN, n = tokG - b * NN;
  const float* xrow = img + ((size_t)b * 197 + 1 + n) * CC;

  for (int p = t; p < HID * 40; p += 512) {
    int j = p / 40, k = p - j * 40;
    w2L[p] = (k < KEEPN) ? w2[(size_t)j * KEEPN + k] : 0.f;
  }

  int jbase = wv * 13;
  uint64_t a64 = (uint64_t)(w1gT + (size_t)jbase * 512);
  uint32_t alo = __builtin_amdgcn_readfirstlane((uint32_t)a64);
  uint32_t ahi = __builtin_amdgcn_readfirstlane((uint32_t)(a64 >> 32));
  uint64_t sbase = ((uint64_t)ahi << 32) | alo;

  float acc[13];
#pragma unroll
  for (int i = 0; i < 13; ++i) acc[i] = 0.f;

  float4 c0 = *(const float4*)(xrow);
  float4 c1 = *(const float4*)(xrow + 4);
  for (int k0 = 0; k0 < CC; k0 += 8) {
    float4 nx0, nx1;
    if (k0 + 8 < CC) {
      nx0 = *(const float4*)(xrow + k0 + 8);
      nx1 = *(const float4*)(xrow + k0 + 12);
    } else {
      nx0 = c0; nx1 = c1;
    }
    float a[8] = {c0.x, c0.y, c0.z, c0.w, c1.x, c1.y, c1.z, c1.w};
    const uint64_t bp = sbase + (uint64_t)k0 * 4;
    f32x8 s0, s1, s2, s3, s4, s5, s6, s7;
    SL8(s0, "0x0");    SL8(s1, "0x800");  SL8(s2, "0x1000"); SL8(s3, "0x1800");
    SL8(s4, "0x2000"); SL8(s5, "0x2800"); SL8(s6, "0x3000"); SL8(s7, "0x3800");
    SWAIT8();
    DOT8(s0, 0); DOT8(s1, 1); DOT8(s2, 2); DOT8(s3, 3);
    DOT8(s4, 4); DOT8(s5, 5); DOT8(s6, 6); DOT8(s7, 7);
    SL8(s0, "0x4000"); SL8(s1, "0x4800"); SL8(s2, "0x5000"); SL8(s3, "0x5800");
    SL8(s4, "0x6000");
    SWAIT5();
    DOT8(s0, 8); DOT8(s1, 9); DOT8(s2, 10); DOT8(s3, 11); DOT8(s4, 12);
    c0 = nx0; c1 = nx1;
  }

  float mu = muG[tokG], rsg = rsG[tokG];
  float nmr = -rsg * mu;
#pragma unroll
  for (int i = 0; i < 13; ++i) {
    int j = jbase + i;
    float h = fmaf(rsg, acc[i], fmaf(nmr, A[j], Bc[j]));
    hL[tok * 105 + j] = 0.5f * h * (1.f + erff(h * 0.70710678118654752f));
  }
  __syncthreads();

  int kg = wv;
  float acc2[5];
#pragma unroll
  for (int i = 0; i < 5; ++i) {
    int k = kg * 5 + i;
    acc2[i] = (k < KEEPN) ? b2[k] : 0.f;
  }
  for (int j = 0; j < HID; ++j) {
    float hv = hL[tok * 105 + j];
#pragma unroll
    for (int i = 0; i < 5; ++i) {
      int k = kg * 5 + i;
      if (k < KEEPN) acc2[i] = fmaf(hv, w2L[j * 40 + k], acc2[i]);
    }
  }
#pragma unroll
  for (int i = 0; i < 5; ++i) {
    int k = kg * 5 + i;
    if (k < KEEPN) y[(size_t)tokG * 40 + k] = acc2[i];
  }
}

// ---------------- score kernel v7: 2 tokens per thread --------------------
// SMEM path delivers ~3 B/cyc/CU (measured R11/R12) — amortize the cap
// stream over 2 tokens: per wave, the same 64 KB cap slice now feeds 2x the
// FMAs. token0 = y*256+tid in [0,4728), token1 = token0+4728 — one guard
// covers both. launch_bounds(256,2): VGPR room for acc0[32]+acc1[32].
__global__ __launch_bounds__(256, 2) void k_score(const float* __restrict__ img,
                                                  const float* __restrict__ cap,
                                                  const float* __restrict__ cinvG,
                                                  const float* __restrict__ ninvG,
                                                  const float* __restrict__ s_imG,
                                                  float* __restrict__ scoreG,
                                                  float* __restrict__ S_T) {
  int j = blockIdx.x;
  int g0 = blockIdx.y * 256 + threadIdx.x;   // token A in [0, 4728)
  if (g0 >= 4728) return;
  int g1 = g0 + 4728;                        // token B in [4728, 9456)

  const float* capj = cap + (size_t)j * MQ * CC;
  const float* spn0 = img + (size_t)g0 * CC;
  const float* spn1 = img + (size_t)g1 * CC;

  float acc0[MQ], acc1[MQ];
#pragma unroll
  for (int m = 0; m < MQ; ++m) { acc0[m] = 0.f; acc1[m] = 0.f; }

  for (int k0 = 0; k0 < CC; k0 += 16) {
    float4 x0 = *(const float4*)(spn0 + k0);
    float4 x1 = *(const float4*)(spn0 + k0 + 4);
    float4 x2 = *(const float4*)(spn0 + k0 + 8);
    float4 x3 = *(const float4*)(spn0 + k0 + 12);
    PIN16(x0, x1, x2, x3);
    float4 y0 = *(const float4*)(spn1 + k0);
    float4 y1 = *(const float4*)(spn1 + k0 + 4);
    float4 y2 = *(const float4*)(spn1 + k0 + 8);
    float4 y3 = *(const float4*)(spn1 + k0 + 12);
    PIN16(y0, y1, y2, y3);
    float a0[16] = {x0.x, x0.y, x0.z, x0.w, x1.x, x1.y, x1.z, x1.w,
                    x2.x, x2.y, x2.z, x2.w, x3.x, x3.y, x3.z, x3.w};
    float a1[16] = {y0.x, y0.y, y0.z, y0.w, y1.x, y1.y, y1.z, y1.w,
                    y2.x, y2.y, y2.z, y2.w, y3.x, y3.y, y3.z, y3.w};
    const float* bp = capj + k0;
    f32x16 q0, q1, q2, q3;
    SL16(q0, "0x0");    SL16(q1, "0x800");  SL16(q2, "0x1000"); SL16(q3, "0x1800");
    SWAITQ();
    DOT16A(q0, acc0, 0, a0); DOT16A(q0, acc1, 0, a1);
    DOT16A(q1, acc0, 1, a0); DOT16A(q1, acc1, 1, a1);
    DOT16A(q2, acc0, 2, a0); DOT16A(q2, acc1, 2, a1);
    DOT16A(q3, acc0, 3, a0); DOT16A(q3, acc1, 3, a1);
    SL16(q0, "0x2000"); SL16(q1, "0x2800"); SL16(q2, "0x3000"); SL16(q3, "0x3800");
    SWAITQ();
    DOT16A(q0, acc0, 4, a0); DOT16A(q0, acc1, 4, a1);
    DOT16A(q1, acc0, 5, a0); DOT16A(q1, acc1, 5, a1);
    DOT16A(q2, acc0, 6, a0); DOT16A(q2, acc1, 6, a1);
    DOT16A(q3, acc0, 7, a0); DOT16A(q3, acc1, 7, a1);
    SL16(q0, "0x4000"); SL16(q1, "0x4800"); SL16(q2, "0x5000"); SL16(q3, "0x5800");
    SWAITQ();
    DOT16A(q0, acc0, 8, a0); DOT16A(q0, acc1, 8, a1);
    DOT16A(q1, acc0, 9, a0); DOT16A(q1, acc1, 9, a1);
    DOT16A(q2, acc0, 10, a0); DOT16A(q2, acc1, 10, a1);
    DOT16A(q3, acc0, 11, a0); DOT16A(q3, acc1, 11, a1);
    SL16(q0, "0x6000"); SL16(q1, "0x6800"); SL16(q2, "0x7000"); SL16(q3, "0x7800");
    SWAITQ();
    DOT16A(q0, acc0, 12, a0); DOT16A(q0, acc1, 12, a1);
    DOT16A(q1, acc0, 13, a0); DOT16A(q1, acc1, 13, a1);
    DOT16A(q2, acc0, 14, a0); DOT16A(q2, acc1, 14, a1);
    DOT16A(q3, acc0, 15, a0); DOT16A(q3, acc1, 15, a1);
    SL16(q0, "0x8000"); SL16(q1, "0x8800"); SL16(q2, "0x9000"); SL16(q3, "0x9800");
    SWAITQ();
    DOT16A(q0, acc0, 16, a0); DOT16A(q0, acc1, 16, a1);
    DOT16A(q1, acc0, 17, a0); DOT16A(q1, acc1, 17, a1);
    DOT16A(q2, acc0, 18, a0); DOT16A(q2, acc1, 18, a1);
    DOT16A(q3, acc0, 19, a0); DOT16A(q3, acc1, 19, a1);
    SL16(q0, "0xA000"); SL16(q1, "0xA800"); SL16(q2, "0xB000"); SL16(q3, "0xB800");
    SWAITQ();
    DOT16A(q0, acc0, 20, a0); DOT16A(q0, acc1, 20, a1);
    DOT16A(q1, acc0, 21, a0); DOT16A(q1, acc1, 21, a1);
    DOT16A(q2, acc0, 22, a0); DOT16A(q2, acc1, 22, a1);
    DOT16A(q3, acc0, 23, a0); DOT16A(q3, acc1, 23, a1);
    SL16(q0, "0xC000"); SL16(q1, "0xC800"); SL16(q2, "0xD000"); SL16(q3, "0xD800");
    SWAITQ();
    DOT16A(q0, acc0, 24, a0); DOT16A(q0, acc1, 24, a1);
    DOT16A(q1, acc0, 25, a0); DOT16A(q1, acc1, 25, a1);
    DOT16A(q2, acc0, 26, a0); DOT16A(q2, acc1, 26, a1);
    DOT16A(q3, acc0, 27, a0); DOT16A(q3, acc1, 27, a1);
    SL16(q0, "0xE000"); SL16(q1, "0xE800"); SL16(q2, "0xF000"); SL16(q3, "0xF800");
    SWAITQ();
    DOT16A(q0, acc0, 28, a0); DOT16A(q0, acc1, 28, a1);
    DOT16A(q1, acc0, 29, a0); DOT16A(q1, acc1, 29, a1);
    DOT16A(q2, acc0, 30, a0); DOT16A(q2, acc1, 30, a1);
    DOT16A(q3, acc0, 31, a0); DOT16A(q3, acc1, 31, a1);
  }

  // ---- epilogue for both tokens ----
#pragma unroll
  for (int pass = 0; pass < 2; ++pass) {
    int gi = pass ? g1 : g0;
    float* accp = pass ? acc1 : acc0;
    int b = gi / 197;
    int tok = gi - b * 197;
    int blk = b * B_T + j;
    float* st = S_T + ((size_t)blk * 197 + tok) * 32;
#pragma unroll
    for (int g = 0; g < 8; ++g) {
      float4 v;
      v.x = accp[g * 4 + 0]; v.y = accp[g * 4 + 1];
      v.z = accp[g * 4 + 2]; v.w = accp[g * 4 + 3];
      *(float4*)(st + g * 4) = v;
    }
    if (tok >= 1) {
      int n = tok - 1;
      float attn = -INFINITY;
#pragma unroll
      for (int m = 0; m < MQ; ++m) attn = fmaxf(attn, accp[m] * cinvG[j * MQ + m]);
      scoreG[(size_t)blk * NN + n] = s_imG[b * NN + n] + attn * ninvG[b * NN + n];
    }
  }
}

// ---------------- partition + softmaxes -> global (small) -----------------
__global__ __launch_bounds__(256, 4) void k_part(const float* __restrict__ scoreG,
                                                 const float* __restrict__ yG,
                                                 const float* __restrict__ scaleG,
                                                 int* __restrict__ keepIG,
                                                 int* __restrict__ nonIG,
                                                 float* __restrict__ nonWG,
                                                 float* __restrict__ wGo) {
  int blk = blockIdx.x;
  int b = blk / B_T;
  int t = threadIdx.x;

  __shared__ float scoreL[NN];
  __shared__ int keepI[NKEEP];
  __shared__ int nonI[NKEEP];
  __shared__ float nonSc[NKEEP];
  __shared__ float yL[NKEEP * 40];
  __shared__ float sc0, sc1;

  if (t < NN) scoreL[t] = scoreG[(size_t)blk * NN + t];
  __syncthreads();

  if (t < NN) {  // exact stable-descending rank
    float ms = scoreL[t];
    int rank = 0;
    for (int q = 0; q < NN; ++q) {
      float sq = scoreL[q];
      rank += (sq > ms) || (sq == ms && q < t);
    }
    if (rank < NKEEP) keepI[rank] = t;
    else { nonI[rank - NKEEP] = t; nonSc[rank - NKEEP] = ms; }
  }
  __syncthreads();

  float scaleV = scaleG[0];
  for (int p = t; p < NKEEP * 40; p += 256) {
    int i = p / 40, k = p - i * 40;
    yL[p] = (k < KEEPN) ? yG[(size_t)(b * NN + keepI[i]) * 40 + k] : 0.f;
  }
  if (t < 64) {
    float v0 = nonSc[t];
    float v1 = (t + 64 < NKEEP) ? nonSc[t + 64] : -INFINITY;
    float mx = waveMax(fmaxf(v0, v1));
    float e = expf(v0 - mx) + ((t + 64 < NKEEP) ? expf(v1 - mx) : 0.f);
    float s = waveSum(e);
    if (t == 0) { sc0 = mx; sc1 = s; }
  }
  __syncthreads();
  if (t < NKEEP) {
    nonWG[(size_t)blk * NKEEP + t] = expf(nonSc[t] - sc0) / sc1;
    keepIG[(size_t)blk * NKEEP + t] = keepI[t];
    nonIG[(size_t)blk * NKEEP + t] = nonI[t];
  }
  if (t >= 128 && t < 128 + KEEPN) {  // softmax over i per k
    int k = t - 128;
    float mx = -INFINITY;
    for (int i = 0; i < NKEEP; ++i) mx = fmaxf(mx, yL[i * 40 + k] * scaleV);
    float s = 0.f;
    for (int i = 0; i < NKEEP; ++i) {
      float e = expf(yL[i * 40 + k] * scaleV - mx);
      yL[i * 40 + k] = e;
      s += e;
    }
    float rs = 1.f / s;
    for (int i = 0; i < NKEEP; ++i) yL[i * 40 + k] *= rs;
  }
  __syncthreads();
  for (int p = t; p < NKEEP * 40; p += 256)
    wGo[(size_t)blk * (NKEEP * 40) + p] = yL[p];
}

// ---------------- main: thread-owns-channel aggr + S-fed c2t --------------
__global__ __launch_bounds__(512, 4) void k_main4(const float* __restrict__ img,
                                                  const float* __restrict__ S_T,
                                                  const int* __restrict__ keepIG,
                                                  const int* __restrict__ nonIG,
                                                  const float* __restrict__ nonWG,
                                                  const float* __restrict__ wG,
                                                  const float* __restrict__ cinvG,
                                                  const float* __restrict__ clsInvG,
                                                  float* __restrict__ out) {
  int blk = blockIdx.x;
  int b = blk / B_T, j = blk - b * B_T;
  int t = threadIdx.x, lane = t & 63, wv = t >> 6;

  __shared__ float wL[NKEEP * 40];   // 15.7 KB
  __shared__ int keepL[NKEEP];
  __shared__ int nonL[NKEEP];
  __shared__ float nonWL[NKEEP];
  __shared__ float cinvL[32];
  __shared__ float red8[40][8];
  __shared__ float aggrInvL[40];
  __shared__ float extRed[8];
  __shared__ float c2tL[TOKS * 33];
  __shared__ float rowM[MQ], colM[TOKS];
  __shared__ float extInvS;

  for (int p = t; p < NKEEP * 40; p += 512)
    wL[p] = wG[(size_t)blk * (NKEEP * 40) + p];
  if (t < NKEEP) {
    keepL[t] = keepIG[(size_t)blk * NKEEP + t];
    nonL[t] = nonIG[(size_t)blk * NKEEP + t];
    nonWL[t] = nonWG[(size_t)blk * NKEEP + t];
  }
  if (t >= 128 && t < 160) cinvL[t - 128] = cinvG[j * MQ + (t - 128)];
  __syncthreads();

  const float* imgsp = img + ((size_t)b * 197 + 1) * CC;

  // ---- phase A: thread owns channel c=t; aggr[c][k] for all 40 k ----
  float acc[40];
#pragma unroll
  for (int k = 0; k < 40; ++k) acc[k] = 0.f;
  {
    const float* wp = wG + (size_t)blk * (NKEEP * 40);
    for (int i = 0; i < NKEEP; ++i) {
      float xv = imgsp[(size_t)keepL[i] * CC + t];  // coalesced per-lane
      const float* bp = wp + i * 40;                // scalar (blk,i uniform)
      f32x8 s0, s1, s2, s3, s4;
      SL8(s0, "0x0"); SL8(s1, "0x20"); SL8(s2, "0x40");
      SL8(s3, "0x60"); SL8(s4, "0x80");
      SWAIT5();
#pragma unroll
      for (int q = 0; q < 8; ++q) {
        acc[q]      = fmaf(s0[q], xv, acc[q]);
        acc[8 + q]  = fmaf(s1[q], xv, acc[8 + q]);
        acc[16 + q] = fmaf(s2[q], xv, acc[16 + q]);
        acc[24 + q] = fmaf(s3[q], xv, acc[24 + q]);
        acc[32 + q] = fmaf(s4[q], xv, acc[32 + q]);
      }
    }
  }
#pragma unroll
  for (int k = 0; k < 40; ++k) {
    float ss = waveSum(acc[k] * acc[k]);
    if (lane == 0) red8[k][wv] = ss;
  }

  // ---- phase A2: extra token (thread owns channel) ----
  float ev = 0.f;
  for (int i = 0; i < NKEEP; ++i)
    ev = fmaf(nonWL[i], imgsp[(size_t)nonL[i] * CC + t], ev);
  {
    float ss = waveSum(ev * ev);
    if (lane == 0) extRed[wv] = ss;
  }
  __syncthreads();
  if (t < 40) {
    float s = 0.f;
#pragma unroll
    for (int q = 0; q < 8; ++q) s += red8[t][q];
    aggrInvL[t] = 1.f / fmaxf(sqrtf(s), 1e-12f);
  }
  if (t == 64) {
    float s = 0.f;
#pragma unroll
    for (int q = 0; q < 8; ++q) s += extRed[q];
    extInvS = 1.f / fmaxf(sqrtf(s), 1e-12f);
  }
  __syncthreads();

  // ---- phase B: c2t columns from S_T; half-wave s owns 3 k's ----
  {
    int m = t & 31;
    int s = t >> 5;  // 0..15
    const float* stb = S_T + ((size_t)blk * 197 + 1) * 32 + m;
    if (s < 13) {
      int k0 = s * 3;  // 13*3 = 39 k's exactly
      float a0 = 0.f, a1 = 0.f, a2 = 0.f;
      for (int i = 0; i < NKEEP; ++i) {
        float sv = stb[(size_t)keepL[i] * 32];
        const float* wr = wL + i * 40 + k0;
        a0 = fmaf(wr[0], sv, a0);
        a1 = fmaf(wr[1], sv, a1);
        a2 = fmaf(wr[2], sv, a2);
      }
      float cm = cinvL[m];
      c2tL[(1 + k0) * 33 + m] = a0 * cm * aggrInvL[k0];
      c2tL[(2 + k0) * 33 + m] = a1 * cm * aggrInvL[k0 + 1];
      c2tL[(3 + k0) * 33 + m] = a2 * cm * aggrInvL[k0 + 2];
    } else if (s == 13) {  // extra column
      float ec = 0.f;
      for (int i = 0; i < NKEEP; ++i)
        ec = fmaf(nonWL[i], stb[(size_t)nonL[i] * 32], ec);
      c2tL[40 * 33 + m] = ec * cinvL[m] * extInvS;
    } else if (s == 14) {  // cls column
      float cv = S_T[((size_t)blk * 197) * 32 + m];
      c2tL[0 * 33 + m] = cv * cinvL[m] * clsInvG[b];
    }
  }
  __syncthreads();

  // ---- phase C: leaky + row/col means ----
  if (t < MQ) {
    float mx = -INFINITY;
    for (int tt = 0; tt < TOKS; ++tt) mx = fmaxf(mx, c2tL[tt * 33 + t]);
    rowM[t] = (mx >= 0.f) ? mx : 0.1f * mx;
  } else if (t >= 64 && t < 64 + TOKS) {
    int tt = t - 64;
    float mx = -INFINITY;
    for (int m = 0; m < MQ; ++m) mx = fmaxf(mx, c2tL[tt * 33 + m]);
    colM[tt] = (mx >= 0.f) ? mx : 0.1f * mx;
  }
  __syncthreads();
  if (t == 0) {
    float r = 0.f, c = 0.f;
    for (int m = 0; m < MQ; ++m) r += rowM[m];
    for (int tt = 0; tt < TOKS; ++tt) c += colM[tt];
    out[b * B_T + j] = r * (1.f / MQ) + c * (1.f / TOKS);
  }
}

extern "C" void kernel_launch(void* const* d_in, const int* in_sizes, int n_in,
                              void* d_out, int out_size, void* d_ws, size_t ws_size,
                              hipStream_t stream) {
  const float* img = (const float*)d_in[0];
  const float* cap = (const float*)d_in[1];
  const float* ln_g = (const float*)d_in[3];
  const float* ln_b = (const float*)d_in[4];
  const float* w1 = (const float*)d_in[5];
  const float* b1 = (const float*)d_in[6];
  const float* w2 = (const float*)d_in[7];
  const float* b2 = (const float*)d_in[8];
  const float* scale = (const float*)d_in[9];
  float* ws = (float*)d_ws;
  float* cinv   = ws;                 // 1536
  float* ninv   = ws + 1536;          // 9408
  float* s_im   = ws + 10944;         // 9408
  float* clsi   = ws + 20352;         // 48
  float* y      = ws + 20400;         // 376320
  float* scoreW = ws + 396720;        // 451584  (overlay: mu/rs/w1gT/A/Bc)
  int*   keepIG = (int*)(ws + 848304);    // 225792
  int*   nonIG  = (int*)(ws + 1074096);   // 225792
  float* nonWG  = ws + 1299888;       // 225792
  float* wGp    = ws + 1525680;       // 9031680 (2304*98*40)
  float* S_T    = ws + 10557360;      // 14524416 (2304*197*32)
  float* muW  = scoreW;               // 9408
  float* rsW  = scoreW + 9408;        // 9408
  float* w1gT = scoreW + 18816;       // 53248
  float* A    = scoreW + 72064;       // 104
  float* Bc   = scoreW + 72168;       // 104
  float* out = (float*)d_out;

  k_prep_img<<<B_V, 256, 0, stream>>>(img, ninv, s_im, clsi);
  k_prep_cap<<<B_T, 256, 0, stream>>>(cap, cinv);
  k_fold<<<104, 256, 0, stream>>>(w1, b1, ln_g, ln_b, w1gT, A, Bc);
  k_ln<<<2352, 256, 0, stream>>>(img, muW, rsW);
  k_gemm<<<147, 512, 0, stream>>>(img, w1gT, A, Bc, muW, rsW, w2, b2, y);
  {
    dim3 g(48, 19);  // 19*256 = 4864 >= 4728 token-pairs
    k_score<<<g, 256, 0, stream>>>(img, cap, cinv, ninv, s_im, scoreW, S_T);
  }
  k_part<<<B_V * B_T, 256, 0, stream>>>(scoreW, y, scale, keepIG, nonIG, nonWG, wGp);
  k_main4<<<B_V * B_T, 512, 0, stream>>>(img, S_T, keepIG, nonIG, nonWG, wGp, cinv,
                                         clsi, out);
}

// Round 14
// 709.949 us; speedup vs baseline: 1.2435x; 1.2435x over previous
//
#include <hip/hip_runtime.h>
#include <math.h>
#include <stdint.h>

#define B_V 48
#define B_T 48
#define MQ 32
#define NN 196
#define CC 512
#define HID 102
#define KEEPN 39
#define NKEEP 98
#define TOKS 41

__device__ __forceinline__ float waveSum(float v) {
#pragma unroll
  for (int off = 32; off > 0; off >>= 1) v += __shfl_xor(v, off, 64);
  return v;
}
__device__ __forceinline__ float waveMax(float v) {
#pragma unroll
  for (int off = 32; off > 0; off >>= 1) v = fmaxf(v, __shfl_xor(v, off, 64));
  return v;
}

// ---------------- prep per image: glo, s_im, ninv, clsInv -----------------
__global__ __launch_bounds__(256) void k_prep_img(const float* __restrict__ img,
                                                  float* __restrict__ ninv,
                                                  float* __restrict__ s_im,
                                                  float* __restrict__ clsInvG) {
  int b = blockIdx.x, t = threadIdx.x;
  __shared__ float glo[CC];
  __shared__ float red[256];
  __shared__ float rgS;
  const float* sp = img + ((size_t)b * 197 + 1) * CC;
  float v0 = 0.f, v1 = 0.f;
  for (int n = 0; n < NN; ++n) {
    v0 += sp[(size_t)n * CC + t];
    v1 += sp[(size_t)n * CC + t + 256];
  }
  v0 *= (1.f / NN); v1 *= (1.f / NN);
  glo[t] = v0; glo[t + 256] = v1;
  red[t] = v0 * v0 + v1 * v1;
  __syncthreads();
  for (int s = 128; s > 0; s >>= 1) {
    if (t < s) red[t] += red[t + s];
    __syncthreads();
  }
  if (t == 0) rgS = 1.f / fmaxf(sqrtf(red[0]), 1e-12f);
  __syncthreads();
  float rg = rgS;
  glo[t] *= rg; glo[t + 256] *= rg;
  __syncthreads();
  int w = t >> 6, lane = t & 63;
  for (int n = w; n < NN; n += 4) {
    const float* row = sp + (size_t)n * CC + lane * 8;
    float4 a = *(const float4*)row;
    float4 bq = *(const float4*)(row + 4);
    const float* gl = glo + lane * 8;
    float ss = a.x * a.x + a.y * a.y + a.z * a.z + a.w * a.w +
               bq.x * bq.x + bq.y * bq.y + bq.z * bq.z + bq.w * bq.w;
    float dt = a.x * gl[0] + a.y * gl[1] + a.z * gl[2] + a.w * gl[3] +
               bq.x * gl[4] + bq.y * gl[5] + bq.z * gl[6] + bq.w * gl[7];
    ss = waveSum(ss);
    dt = waveSum(dt);
    if (lane == 0) {
      float nv = 1.f / fmaxf(sqrtf(ss), 1e-12f);
      ninv[b * NN + n] = nv;
      s_im[b * NN + n] = dt * nv;
    }
  }
  __syncthreads();
  {  // cls norm (j-independent hoist)
    const float* cls = img + (size_t)b * 197 * CC;
    float c0v = cls[t], c1v = cls[t + 256];
    red[t] = c0v * c0v + c1v * c1v;
    __syncthreads();
    for (int s = 128; s > 0; s >>= 1) {
      if (t < s) red[t] += red[t + s];
      __syncthreads();
    }
    if (t == 0) clsInvG[b] = 1.f / fmaxf(sqrtf(red[0]), 1e-12f);
  }
}

// ---------------- prep per caption: inverse norms -------------------------
__global__ __launch_bounds__(256) void k_prep_cap(const float* __restrict__ cap,
                                                  float* __restrict__ cinv) {
  int j = blockIdx.x, t = threadIdx.x, w = t >> 6, lane = t & 63;
  for (int m = w; m < MQ; m += 4) {
    const float* row = cap + ((size_t)j * MQ + m) * CC + lane * 8;
    float4 a = *(const float4*)row;
    float4 bq = *(const float4*)(row + 4);
    float ss = a.x * a.x + a.y * a.y + a.z * a.z + a.w * a.w +
               bq.x * bq.x + bq.y * bq.y + bq.z * bq.z + bq.w * bq.w;
    ss = waveSum(ss);
    if (lane == 0) cinv[j * MQ + m] = 1.f / fmaxf(sqrtf(ss), 1e-12f);
  }
}

// ---------------- fold LN into w1 ----------------
__global__ __launch_bounds__(256) void k_fold(const float* __restrict__ w1,
                                              const float* __restrict__ b1,
                                              const float* __restrict__ ln_g,
                                              const float* __restrict__ ln_b,
                                              float* __restrict__ w1gT,
                                              float* __restrict__ A,
                                              float* __restrict__ Bc) {
  int j = blockIdx.x, t = threadIdx.x;
  __shared__ float r1[4], r2[4];
  float v0 = 0.f, v1 = 0.f, ba = 0.f;
  if (j < HID) {
    float wv0 = w1[(size_t)t * HID + j];
    float wv1 = w1[(size_t)(t + 256) * HID + j];
    v0 = ln_g[t] * wv0;
    v1 = ln_g[t + 256] * wv1;
    ba = ln_b[t] * wv0 + ln_b[t + 256] * wv1;
  }
  w1gT[(size_t)j * 512 + t] = v0;
  w1gT[(size_t)j * 512 + t + 256] = v1;
  float aa = waveSum(v0 + v1);
  float bb = waveSum(ba);
  int wv = t >> 6, lane = t & 63;
  if (lane == 0) { r1[wv] = aa; r2[wv] = bb; }
  __syncthreads();
  if (t == 0) {
    float sa = r1[0] + r1[1] + r1[2] + r1[3];
    float sb = r2[0] + r2[1] + r2[2] + r2[3];
    A[j] = (j < HID) ? sa : 0.f;
    Bc[j] = (j < HID) ? (sb + b1[j]) : 0.f;
  }
}

// ---------------- per-token LN stats ----------------
__global__ __launch_bounds__(256) void k_ln(const float* __restrict__ img,
                                            float* __restrict__ muG,
                                            float* __restrict__ rsG) {
  int t = threadIdx.x, wv = t >> 6, lane = t & 63;
  int tokG = blockIdx.x * 4 + wv;
  int b = tokG / NN, n = tokG - b * NN;
  const float* row = img + ((size_t)b * 197 + 1 + n) * CC + lane * 8;
  float4 a = *(const float4*)row;
  float4 bq = *(const float4*)(row + 4);
  float sm = a.x + a.y + a.z + a.w + bq.x + bq.y + bq.z + bq.w;
  float ss = a.x * a.x + a.y * a.y + a.z * a.z + a.w * a.w +
             bq.x * bq.x + bq.y * bq.y + bq.z * bq.z + bq.w * bq.w;
  sm = waveSum(sm);
  ss = waveSum(ss);
  if (lane == 0) {
    float mu = sm * (1.f / CC);
    float var = ss * (1.f / CC) - mu * mu;
    muG[tokG] = mu;
    rsG[tokG] = rsqrtf(var + 1e-5f);
  }
}

// ---------------- s_load helpers ----------------
typedef __attribute__((ext_vector_type(8))) float f32x8;
typedef __attribute__((ext_vector_type(16))) float f32x16;

#define SL8(dst, off_lit) \
  asm volatile("s_load_dwordx8 %0, %1, " off_lit : "=s"(dst) : "s"(bp))

#define SL16(dst, off_lit) \
  asm volatile("s_load_dwordx16 %0, %1, " off_lit : "=s"(dst) : "s"(bp))

#define SWAIT8() \
  asm volatile("s_waitcnt lgkmcnt(0)" \
               : "+s"(s0), "+s"(s1), "+s"(s2), "+s"(s3), \
                 "+s"(s4), "+s"(s5), "+s"(s6), "+s"(s7))

#define SWAIT5() \
  asm volatile("s_waitcnt lgkmcnt(0)" \
               : "+s"(s0), "+s"(s1), "+s"(s2), "+s"(s3), "+s"(s4))

#define SWAITQ() \
  asm volatile("s_waitcnt lgkmcnt(0)" : "+s"(q0), "+s"(q1), "+s"(q2), "+s"(q3))

#define DOT8(S, I) do { float t_ = acc[I]; \
  t_ = fmaf(S[0], a[0], t_); t_ = fmaf(S[1], a[1], t_); \
  t_ = fmaf(S[2], a[2], t_); t_ = fmaf(S[3], a[3], t_); \
  t_ = fmaf(S[4], a[4], t_); t_ = fmaf(S[5], a[5], t_); \
  t_ = fmaf(S[6], a[6], t_); t_ = fmaf(S[7], a[7], t_); \
  acc[I] = t_; } while (0)

#define DOT16(S, I) do { float t_ = acc[I]; \
  t_ = fmaf(S[0], a[0], t_);   t_ = fmaf(S[1], a[1], t_); \
  t_ = fmaf(S[2], a[2], t_);   t_ = fmaf(S[3], a[3], t_); \
  t_ = fmaf(S[4], a[4], t_);   t_ = fmaf(S[5], a[5], t_); \
  t_ = fmaf(S[6], a[6], t_);   t_ = fmaf(S[7], a[7], t_); \
  t_ = fmaf(S[8], a[8], t_);   t_ = fmaf(S[9], a[9], t_); \
  t_ = fmaf(S[10], a[10], t_); t_ = fmaf(S[11], a[11], t_); \
  t_ = fmaf(S[12], a[12], t_); t_ = fmaf(S[13], a[13], t_); \
  t_ = fmaf(S[14], a[14], t_); t_ = fmaf(S[15], a[15], t_); \
  acc[I] = t_; } while (0)

// Empty volatile asm: pins loaded floats into registers exactly once.
#define PIN16(a0, a1, a2, a3) \
  asm volatile("" : "+v"(a0.x), "+v"(a0.y), "+v"(a0.z), "+v"(a0.w), \
                    "+v"(a1.x), "+v"(a1.y), "+v"(a1.z), "+v"(a1.w), \
                    "+v"(a2.x), "+v"(a2.y), "+v"(a2.z), "+v"(a2.w), \
                    "+v"(a3.x), "+v"(a3.y), "+v"(a3.z), "+v"(a3.w))

// ---------------- fused x@w1g (+gelu) @ w2 per 64-token tile --------------
__global__ __launch_bounds__(512, 2) void k_gemm(const float* __restrict__ img,
                                                 const float* __restrict__ w1gT,
                                                 const float* __restrict__ A,
                                                 const float* __restrict__ Bc,
                                                 const float* __restrict__ muG,
                                                 const float* __restrict__ rsG,
                                                 const float* __restrict__ w2,
                                                 const float* __restrict__ b2,
                                                 float* __restrict__ y) {
  __shared__ float hL[64 * 105];
  __shared__ float w2L[HID * 40];
  int t = threadIdx.x;
  int tok = t & 63, wv = t >> 6;
  int tokG = blockIdx.x * 64 + tok;
  int b = tokG / NN, n = tokG - b * NN;
  const float* xrow = img + ((size_t)b * 197 + 1 + n) * CC;

  for (int p = t; p < HID * 40; p += 512) {
    int j = p / 40, k = p - j * 40;
    w2L[p] = (k < KEEPN) ? w2[(size_t)j * KEEPN + k] : 0.f;
  }

  int jbase = wv * 13;
  uint64_t a64 = (uint64_t)(w1gT + (size_t)jbase * 512);
  uint32_t alo = __builtin_amdgcn_readfirstlane((uint32_t)a64);
  uint32_t ahi = __builtin_amdgcn_readfirstlane((uint32_t)(a64 >> 32));
  uint64_t sbase = ((uint64_t)ahi << 32) | alo;

  float acc[13];
#pragma unroll
  for (int i = 0; i < 13; ++i) acc[i] = 0.f;

  float4 c0 = *(const float4*)(xrow);
  float4 c1 = *(const float4*)(xrow + 4);
  for (int k0 = 0; k0 < CC; k0 += 8) {
    float4 nx0, nx1;
    if (k0 + 8 < CC) {
      nx0 = *(const float4*)(xrow + k0 + 8);
      nx1 = *(const float4*)(xrow + k0 + 12);
    } else {
      nx0 = c0; nx1 = c1;
    }
    float a[8] = {c0.x, c0.y, c0.z, c0.w, c1.x, c1.y, c1.z, c1.w};
    const uint64_t bp = sbase + (uint64_t)k0 * 4;
    f32x8 s0, s1, s2, s3, s4, s5, s6, s7;
    SL8(s0, "0x0");    SL8(s1, "0x800");  SL8(s2, "0x1000"); SL8(s3, "0x1800");
    SL8(s4, "0x2000"); SL8(s5, "0x2800"); SL8(s6, "0x3000"); SL8(s7, "0x3800");
    SWAIT8();
    DOT8(s0, 0); DOT8(s1, 1); DOT8(s2, 2); DOT8(s3, 3);
    DOT8(s4, 4); DOT8(s5, 5); DOT8(s6, 6); DOT8(s7, 7);
    SL8(s0, "0x4000"); SL8(s1, "0x4800"); SL8(s2, "0x5000"); SL8(s3, "0x5800");
    SL8(s4, "0x6000");
    SWAIT5();
    DOT8(s0, 8); DOT8(s1, 9); DOT8(s2, 10); DOT8(s3, 11); DOT8(s4, 12);
    c0 = nx0; c1 = nx1;
  }

  float mu = muG[tokG], rsg = rsG[tokG];
  float nmr = -rsg * mu;
#pragma unroll
  for (int i = 0; i < 13; ++i) {
    int j = jbase + i;
    float h = fmaf(rsg, acc[i], fmaf(nmr, A[j], Bc[j]));
    hL[tok * 105 + j] = 0.5f * h * (1.f + erff(h * 0.70710678118654752f));
  }
  __syncthreads();

  int kg = wv;
  float acc2[5];
#pragma unroll
  for (int i = 0; i < 5; ++i) {
    int k = kg * 5 + i;
    acc2[i] = (k < KEEPN) ? b2[k] : 0.f;
  }
  for (int j = 0; j < HID; ++j) {
    float hv = hL[tok * 105 + j];
#pragma unroll
    for (int i = 0; i < 5; ++i) {
      int k = kg * 5 + i;
      if (k < KEEPN) acc2[i] = fmaf(hv, w2L[j * 40 + k], acc2[i]);
    }
  }
#pragma unroll
  for (int i = 0; i < 5; ++i) {
    int k = kg * 5 + i;
    if (k < KEEPN) y[(size_t)tokG * 40 + k] = acc2[i];
  }
}

// ---------------- score kernel v8 ----------------
// R12-passing body (grid (48,37), SL16, PIN16), single change:
// launch_bounds(256, 8) -> ~7 co-resident blocks/CU (28 waves/CU) to cover
// the lgkmcnt(0) SMEM drains. R12 VGPR=36 fits the 64-VGPR cap with slack.
__global__ __launch_bounds__(256, 8) void k_score(const float* __restrict__ img,
                                                  const float* __restrict__ cap,
                                                  const float* __restrict__ cinvG,
                                                  const float* __restrict__ ninvG,
                                                  const float* __restrict__ s_imG,
                                                  float* __restrict__ scoreG,
                                                  float* __restrict__ S_T) {
  int j = blockIdx.x;
  int gi = blockIdx.y * 256 + threadIdx.x;
  if (gi >= 48 * 197) return;
  int b = gi / 197;
  int tok = gi - b * 197;
  int blk = b * B_T + j;

  const float* capj = cap + (size_t)j * MQ * CC;
  const float* spn = img + (size_t)gi * CC;  // == (b*197+tok)*CC

  float acc[MQ];
#pragma unroll
  for (int m = 0; m < MQ; ++m) acc[m] = 0.f;

  for (int k0 = 0; k0 < CC; k0 += 16) {
    float4 a0 = *(const float4*)(spn + k0);
    float4 a1 = *(const float4*)(spn + k0 + 4);
    float4 a2 = *(const float4*)(spn + k0 + 8);
    float4 a3 = *(const float4*)(spn + k0 + 12);
    PIN16(a0, a1, a2, a3);  // materialize the row chunk exactly once
    float a[16] = {a0.x, a0.y, a0.z, a0.w, a1.x, a1.y, a1.z, a1.w,
                   a2.x, a2.y, a2.z, a2.w, a3.x, a3.y, a3.z, a3.w};
    const float* bp = capj + k0;
    f32x16 q0, q1, q2, q3;
    SL16(q0, "0x0");    SL16(q1, "0x800");  SL16(q2, "0x1000"); SL16(q3, "0x1800");
    SWAITQ();
    DOT16(q0, 0); DOT16(q1, 1); DOT16(q2, 2); DOT16(q3, 3);
    SL16(q0, "0x2000"); SL16(q1, "0x2800"); SL16(q2, "0x3000"); SL16(q3, "0x3800");
    SWAITQ();
    DOT16(q0, 4); DOT16(q1, 5); DOT16(q2, 6); DOT16(q3, 7);
    SL16(q0, "0x4000"); SL16(q1, "0x4800"); SL16(q2, "0x5000"); SL16(q3, "0x5800");
    SWAITQ();
    DOT16(q0, 8); DOT16(q1, 9); DOT16(q2, 10); DOT16(q3, 11);
    SL16(q0, "0x6000"); SL16(q1, "0x6800"); SL16(q2, "0x7000"); SL16(q3, "0x7800");
    SWAITQ();
    DOT16(q0, 12); DOT16(q1, 13); DOT16(q2, 14); DOT16(q3, 15);
    SL16(q0, "0x8000"); SL16(q1, "0x8800"); SL16(q2, "0x9000"); SL16(q3, "0x9800");
    SWAITQ();
    DOT16(q0, 16); DOT16(q1, 17); DOT16(q2, 18); DOT16(q3, 19);
    SL16(q0, "0xA000"); SL16(q1, "0xA800"); SL16(q2, "0xB000"); SL16(q3, "0xB800");
    SWAITQ();
    DOT16(q0, 20); DOT16(q1, 21); DOT16(q2, 22); DOT16(q3, 23);
    SL16(q0, "0xC000"); SL16(q1, "0xC800"); SL16(q2, "0xD000"); SL16(q3, "0xD800");
    SWAITQ();
    DOT16(q0, 24); DOT16(q1, 25); DOT16(q2, 26); DOT16(q3, 27);
    SL16(q0, "0xE000"); SL16(q1, "0xE800"); SL16(q2, "0xF000"); SL16(q3, "0xF800");
    SWAITQ();
    DOT16(q0, 28); DOT16(q1, 29); DOT16(q2, 30); DOT16(q3, 31);
  }

  float* st = S_T + ((size_t)blk * 197 + tok) * 32;
#pragma unroll
  for (int g = 0; g < 8; ++g) {
    float4 v;
    v.x = acc[g * 4 + 0]; v.y = acc[g * 4 + 1];
    v.z = acc[g * 4 + 2]; v.w = acc[g * 4 + 3];
    *(float4*)(st + g * 4) = v;
  }

  if (tok >= 1) {
    int n = tok - 1;
    float attn = -INFINITY;
#pragma unroll
    for (int m = 0; m < MQ; ++m) attn = fmaxf(attn, acc[m] * cinvG[j * MQ + m]);
    scoreG[(size_t)blk * NN + n] = s_imG[b * NN + n] + attn * ninvG[b * NN + n];
  }
}

// ---------------- partition + softmaxes -> global (small) -----------------
__global__ __launch_bounds__(256, 4) void k_part(const float* __restrict__ scoreG,
                                                 const float* __restrict__ yG,
                                                 const float* __restrict__ scaleG,
                                                 int* __restrict__ keepIG,
                                                 int* __restrict__ nonIG,
                                                 float* __restrict__ nonWG,
                                                 float* __restrict__ wGo) {
  int blk = blockIdx.x;
  int b = blk / B_T;
  int t = threadIdx.x;

  __shared__ float scoreL[NN];
  __shared__ int keepI[NKEEP];
  __shared__ int nonI[NKEEP];
  __shared__ float nonSc[NKEEP];
  __shared__ float yL[NKEEP * 40];
  __shared__ float sc0, sc1;

  if (t < NN) scoreL[t] = scoreG[(size_t)blk * NN + t];
  __syncthreads();

  if (t < NN) {  // exact stable-descending rank
    float ms = scoreL[t];
    int rank = 0;
    for (int q = 0; q < NN; ++q) {
      float sq = scoreL[q];
      rank += (sq > ms) || (sq == ms && q < t);
    }
    if (rank < NKEEP) keepI[rank] = t;
    else { nonI[rank - NKEEP] = t; nonSc[rank - NKEEP] = ms; }
  }
  __syncthreads();

  float scaleV = scaleG[0];
  for (int p = t; p < NKEEP * 40; p += 256) {
    int i = p / 40, k = p - i * 40;
    yL[p] = (k < KEEPN) ? yG[(size_t)(b * NN + keepI[i]) * 40 + k] : 0.f;
  }
  if (t < 64) {
    float v0 = nonSc[t];
    float v1 = (t + 64 < NKEEP) ? nonSc[t + 64] : -INFINITY;
    float mx = waveMax(fmaxf(v0, v1));
    float e = expf(v0 - mx) + ((t + 64 < NKEEP) ? expf(v1 - mx) : 0.f);
    float s = waveSum(e);
    if (t == 0) { sc0 = mx; sc1 = s; }
  }
  __syncthreads();
  if (t < NKEEP) {
    nonWG[(size_t)blk * NKEEP + t] = expf(nonSc[t] - sc0) / sc1;
    keepIG[(size_t)blk * NKEEP + t] = keepI[t];
    nonIG[(size_t)blk * NKEEP + t] = nonI[t];
  }
  if (t >= 128 && t < 128 + KEEPN) {  // softmax over i per k
    int k = t - 128;
    float mx = -INFINITY;
    for (int i = 0; i < NKEEP; ++i) mx = fmaxf(mx, yL[i * 40 + k] * scaleV);
    float s = 0.f;
    for (int i = 0; i < NKEEP; ++i) {
      float e = expf(yL[i * 40 + k] * scaleV - mx);
      yL[i * 40 + k] = e;
      s += e;
    }
    float rs = 1.f / s;
    for (int i = 0; i < NKEEP; ++i) yL[i * 40 + k] *= rs;
  }
  __syncthreads();
  for (int p = t; p < NKEEP * 40; p += 256)
    wGo[(size_t)blk * (NKEEP * 40) + p] = yL[p];
}

// ---------------- main: thread-owns-channel aggr + S-fed c2t --------------
__global__ __launch_bounds__(512, 4) void k_main4(const float* __restrict__ img,
                                                  const float* __restrict__ S_T,
                                                  const int* __restrict__ keepIG,
                                                  const int* __restrict__ nonIG,
                                                  const float* __restrict__ nonWG,
                                                  const float* __restrict__ wG,
                                                  const float* __restrict__ cinvG,
                                                  const float* __restrict__ clsInvG,
                                                  float* __restrict__ out) {
  int blk = blockIdx.x;
  int b = blk / B_T, j = blk - b * B_T;
  int t = threadIdx.x, lane = t & 63, wv = t >> 6;

  __shared__ float wL[NKEEP * 40];   // 15.7 KB
  __shared__ int keepL[NKEEP];
  __shared__ int nonL[NKEEP];
  __shared__ float nonWL[NKEEP];
  __shared__ float cinvL[32];
  __shared__ float red8[40][8];
  __shared__ float aggrInvL[40];
  __shared__ float extRed[8];
  __shared__ float c2tL[TOKS * 33];
  __shared__ float rowM[MQ], colM[TOKS];
  __shared__ float extInvS;

  for (int p = t; p < NKEEP * 40; p += 512)
    wL[p] = wG[(size_t)blk * (NKEEP * 40) + p];
  if (t < NKEEP) {
    keepL[t] = keepIG[(size_t)blk * NKEEP + t];
    nonL[t] = nonIG[(size_t)blk * NKEEP + t];
    nonWL[t] = nonWG[(size_t)blk * NKEEP + t];
  }
  if (t >= 128 && t < 160) cinvL[t - 128] = cinvG[j * MQ + (t - 128)];
  __syncthreads();

  const float* imgsp = img + ((size_t)b * 197 + 1) * CC;

  // ---- phase A: thread owns channel c=t; aggr[c][k] for all 40 k ----
  float acc[40];
#pragma unroll
  for (int k = 0; k < 40; ++k) acc[k] = 0.f;
  {
    const float* wp = wG + (size_t)blk * (NKEEP * 40);
    for (int i = 0; i < NKEEP; ++i) {
      float xv = imgsp[(size_t)keepL[i] * CC + t];  // coalesced per-lane
      const float* bp = wp + i * 40;                // scalar (blk,i uniform)
      f32x8 s0, s1, s2, s3, s4;
      SL8(s0, "0x0"); SL8(s1, "0x20"); SL8(s2, "0x40");
      SL8(s3, "0x60"); SL8(s4, "0x80");
      SWAIT5();
#pragma unroll
      for (int q = 0; q < 8; ++q) {
        acc[q]      = fmaf(s0[q], xv, acc[q]);
        acc[8 + q]  = fmaf(s1[q], xv, acc[8 + q]);
        acc[16 + q] = fmaf(s2[q], xv, acc[16 + q]);
        acc[24 + q] = fmaf(s3[q], xv, acc[24 + q]);
        acc[32 + q] = fmaf(s4[q], xv, acc[32 + q]);
      }
    }
  }
#pragma unroll
  for (int k = 0; k < 40; ++k) {
    float ss = waveSum(acc[k] * acc[k]);
    if (lane == 0) red8[k][wv] = ss;
  }

  // ---- phase A2: extra token (thread owns channel) ----
  float ev = 0.f;
  for (int i = 0; i < NKEEP; ++i)
    ev = fmaf(nonWL[i], imgsp[(size_t)nonL[i] * CC + t], ev);
  {
    float ss = waveSum(ev * ev);
    if (lane == 0) extRed[wv] = ss;
  }
  __syncthreads();
  if (t < 40) {
    float s = 0.f;
#pragma unroll
    for (int q = 0; q < 8; ++q) s += red8[t][q];
    aggrInvL[t] = 1.f / fmaxf(sqrtf(s), 1e-12f);
  }
  if (t == 64) {
    float s = 0.f;
#pragma unroll
    for (int q = 0; q < 8; ++q) s += extRed[q];
    extInvS = 1.f / fmaxf(sqrtf(s), 1e-12f);
  }
  __syncthreads();

  // ---- phase B: c2t columns from S_T; half-wave s owns 3 k's ----
  {
    int m = t & 31;
    int s = t >> 5;  // 0..15
    const float* stb = S_T + ((size_t)blk * 197 + 1) * 32 + m;
    if (s < 13) {
      int k0 = s * 3;  // 13*3 = 39 k's exactly
      float a0 = 0.f, a1 = 0.f, a2 = 0.f;
      for (int i = 0; i < NKEEP; ++i) {
        float sv = stb[(size_t)keepL[i] * 32];
        const float* wr = wL + i * 40 + k0;
        a0 = fmaf(wr[0], sv, a0);
        a1 = fmaf(wr[1], sv, a1);
        a2 = fmaf(wr[2], sv, a2);
      }
      float cm = cinvL[m];
      c2tL[(1 + k0) * 33 + m] = a0 * cm * aggrInvL[k0];
      c2tL[(2 + k0) * 33 + m] = a1 * cm * aggrInvL[k0 + 1];
      c2tL[(3 + k0) * 33 + m] = a2 * cm * aggrInvL[k0 + 2];
    } else if (s == 13) {  // extra column
      float ec = 0.f;
      for (int i = 0; i < NKEEP; ++i)
        ec = fmaf(nonWL[i], stb[(size_t)nonL[i] * 32], ec);
      c2tL[40 * 33 + m] = ec * cinvL[m] * extInvS;
    } else if (s == 14) {  // cls column
      float cv = S_T[((size_t)blk * 197) * 32 + m];
      c2tL[0 * 33 + m] = cv * cinvL[m] * clsInvG[b];
    }
  }
  __syncthreads();

  // ---- phase C: leaky + row/col means ----
  if (t < MQ) {
    float mx = -INFINITY;
    for (int tt = 0; tt < TOKS; ++tt) mx = fmaxf(mx, c2tL[tt * 33 + t]);
    rowM[t] = (mx >= 0.f) ? mx : 0.1f * mx;
  } else if (t >= 64 && t < 64 + TOKS) {
    int tt = t - 64;
    float mx = -INFINITY;
    for (int m = 0; m < MQ; ++m) mx = fmaxf(mx, c2tL[tt * 33 + m]);
    colM[tt] = (mx >= 0.f) ? mx : 0.1f * mx;
  }
  __syncthreads();
  if (t == 0) {
    float r = 0.f, c = 0.f;
    for (int m = 0; m < MQ; ++m) r += rowM[m];
    for (int tt = 0; tt < TOKS; ++tt) c += colM[tt];
    out[b * B_T + j] = r * (1.f / MQ) + c * (1.f / TOKS);
  }
}

extern "C" void kernel_launch(void* const* d_in, const int* in_sizes, int n_in,
                              void* d_out, int out_size, void* d_ws, size_t ws_size,
                              hipStream_t stream) {
  const float* img = (const float*)d_in[0];
  const float* cap = (const float*)d_in[1];
  const float* ln_g = (const float*)d_in[3];
  const float* ln_b = (const float*)d_in[4];
  const float* w1 = (const float*)d_in[5];
  const float* b1 = (const float*)d_in[6];
  const float* w2 = (const float*)d_in[7];
  const float* b2 = (const float*)d_in[8];
  const float* scale = (const float*)d_in[9];
  float* ws = (float*)d_ws;
  float* cinv   = ws;                 // 1536
  float* ninv   = ws + 1536;          // 9408
  float* s_im   = ws + 10944;         // 9408
  float* clsi   = ws + 20352;         // 48
  float* y      = ws + 20400;         // 376320
  float* scoreW = ws + 396720;        // 451584  (overlay: mu/rs/w1gT/A/Bc)
  int*   keepIG = (int*)(ws + 848304);    // 225792
  int*   nonIG  = (int*)(ws + 1074096);   // 225792
  float* nonWG  = ws + 1299888;       // 225792
  float* wGp    = ws + 1525680;       // 9031680 (2304*98*40)
  float* S_T    = ws + 10557360;      // 14524416 (2304*197*32)
  float* muW  = scoreW;               // 9408
  float* rsW  = scoreW + 9408;        // 9408
  float* w1gT = scoreW + 18816;       // 53248
  float* A    = scoreW + 72064;       // 104
  float* Bc   = scoreW + 72168;       // 104
  float* out = (float*)d_out;

  k_prep_img<<<B_V, 256, 0, stream>>>(img, ninv, s_im, clsi);
  k_prep_cap<<<B_T, 256, 0, stream>>>(cap, cinv);
  k_fold<<<104, 256, 0, stream>>>(w1, b1, ln_g, ln_b, w1gT, A, Bc);
  k_ln<<<2352, 256, 0, stream>>>(img, muW, rsW);
  k_gemm<<<147, 512, 0, stream>>>(img, w1gT, A, Bc, muW, rsW, w2, b2, y);
  {
    dim3 g(48, 37);
    k_score<<<g, 256, 0, stream>>>(img, cap, cinv, ninv, s_im, scoreW, S_T);
  }
  k_part<<<B_V * B_T, 256, 0, stream>>>(scoreW, y, scale, keepIG, nonIG, nonWG, wGp);
  k_main4<<<B_V * B_T, 512, 0, stream>>>(img, S_T, keepIG, nonIG, nonWG, wGp, cinv,
                                         clsi, out);
}

// Round 15
// 653.592 us; speedup vs baseline: 1.3507x; 1.0862x over previous
//
#include <hip/hip_runtime.h>
#include <math.h>
#include <stdint.h>

#define B_V 48
#define B_T 48
#define MQ 32
#define NN 196
#define CC 512
#define HID 102
#define KEEPN 39
#define NKEEP 98
#define TOKS 41

__device__ __forceinline__ float waveSum(float v) {
#pragma unroll
  for (int off = 32; off > 0; off >>= 1) v += __shfl_xor(v, off, 64);
  return v;
}
__device__ __forceinline__ float waveMax(float v) {
#pragma unroll
  for (int off = 32; off > 0; off >>= 1) v = fmaxf(v, __shfl_xor(v, off, 64));
  return v;
}

// ---------------- prep per image: glo, s_im, ninv, clsInv -----------------
__global__ __launch_bounds__(256) void k_prep_img(const float* __restrict__ img,
                                                  float* __restrict__ ninv,
                                                  float* __restrict__ s_im,
                                                  float* __restrict__ clsInvG) {
  int b = blockIdx.x, t = threadIdx.x;
  __shared__ float glo[CC];
  __shared__ float red[256];
  __shared__ float rgS;
  const float* sp = img + ((size_t)b * 197 + 1) * CC;
  float v0 = 0.f, v1 = 0.f;
  for (int n = 0; n < NN; ++n) {
    v0 += sp[(size_t)n * CC + t];
    v1 += sp[(size_t)n * CC + t + 256];
  }
  v0 *= (1.f / NN); v1 *= (1.f / NN);
  glo[t] = v0; glo[t + 256] = v1;
  red[t] = v0 * v0 + v1 * v1;
  __syncthreads();
  for (int s = 128; s > 0; s >>= 1) {
    if (t < s) red[t] += red[t + s];
    __syncthreads();
  }
  if (t == 0) rgS = 1.f / fmaxf(sqrtf(red[0]), 1e-12f);
  __syncthreads();
  float rg = rgS;
  glo[t] *= rg; glo[t + 256] *= rg;
  __syncthreads();
  int w = t >> 6, lane = t & 63;
  for (int n = w; n < NN; n += 4) {
    const float* row = sp + (size_t)n * CC + lane * 8;
    float4 a = *(const float4*)row;
    float4 bq = *(const float4*)(row + 4);
    const float* gl = glo + lane * 8;
    float ss = a.x * a.x + a.y * a.y + a.z * a.z + a.w * a.w +
               bq.x * bq.x + bq.y * bq.y + bq.z * bq.z + bq.w * bq.w;
    float dt = a.x * gl[0] + a.y * gl[1] + a.z * gl[2] + a.w * gl[3] +
               bq.x * gl[4] + bq.y * gl[5] + bq.z * gl[6] + bq.w * gl[7];
    ss = waveSum(ss);
    dt = waveSum(dt);
    if (lane == 0) {
      float nv = 1.f / fmaxf(sqrtf(ss), 1e-12f);
      ninv[b * NN + n] = nv;
      s_im[b * NN + n] = dt * nv;
    }
  }
  __syncthreads();
  {  // cls norm (j-independent hoist)
    const float* cls = img + (size_t)b * 197 * CC;
    float c0v = cls[t], c1v = cls[t + 256];
    red[t] = c0v * c0v + c1v * c1v;
    __syncthreads();
    for (int s = 128; s > 0; s >>= 1) {
      if (t < s) red[t] += red[t + s];
      __syncthreads();
    }
    if (t == 0) clsInvG[b] = 1.f / fmaxf(sqrtf(red[0]), 1e-12f);
  }
}

// ---------------- prep per caption: inverse norms -------------------------
__global__ __launch_bounds__(256) void k_prep_cap(const float* __restrict__ cap,
                                                  float* __restrict__ cinv) {
  int j = blockIdx.x, t = threadIdx.x, w = t >> 6, lane = t & 63;
  for (int m = w; m < MQ; m += 4) {
    const float* row = cap + ((size_t)j * MQ + m) * CC + lane * 8;
    float4 a = *(const float4*)row;
    float4 bq = *(const float4*)(row + 4);
    float ss = a.x * a.x + a.y * a.y + a.z * a.z + a.w * a.w +
               bq.x * bq.x + bq.y * bq.y + bq.z * bq.z + bq.w * bq.w;
    ss = waveSum(ss);
    if (lane == 0) cinv[j * MQ + m] = 1.f / fmaxf(sqrtf(ss), 1e-12f);
  }
}

// ---------------- fold LN into w1 ----------------
__global__ __launch_bounds__(256) void k_fold(const float* __restrict__ w1,
                                              const float* __restrict__ b1,
                                              const float* __restrict__ ln_g,
                                              const float* __restrict__ ln_b,
                                              float* __restrict__ w1gT,
                                              float* __restrict__ A,
                                              float* __restrict__ Bc) {
  int j = blockIdx.x, t = threadIdx.x;
  __shared__ float r1[4], r2[4];
  float v0 = 0.f, v1 = 0.f, ba = 0.f;
  if (j < HID) {
    float wv0 = w1[(size_t)t * HID + j];
    float wv1 = w1[(size_t)(t + 256) * HID + j];
    v0 = ln_g[t] * wv0;
    v1 = ln_g[t + 256] * wv1;
    ba = ln_b[t] * wv0 + ln_b[t + 256] * wv1;
  }
  w1gT[(size_t)j * 512 + t] = v0;
  w1gT[(size_t)j * 512 + t + 256] = v1;
  float aa = waveSum(v0 + v1);
  float bb = waveSum(ba);
  int wv = t >> 6, lane = t & 63;
  if (lane == 0) { r1[wv] = aa; r2[wv] = bb; }
  __syncthreads();
  if (t == 0) {
    float sa = r1[0] + r1[1] + r1[2] + r1[3];
    float sb = r2[0] + r2[1] + r2[2] + r2[3];
    A[j] = (j < HID) ? sa : 0.f;
    Bc[j] = (j < HID) ? (sb + b1[j]) : 0.f;
  }
}

// ---------------- per-token LN stats ----------------
__global__ __launch_bounds__(256) void k_ln(const float* __restrict__ img,
                                            float* __restrict__ muG,
                                            float* __restrict__ rsG) {
  int t = threadIdx.x, wv = t >> 6, lane = t & 63;
  int tokG = blockIdx.x * 4 + wv;
  int b = tokG / NN, n = tokG - b * NN;
  const float* row = img + ((size_t)b * 197 + 1 + n) * CC + lane * 8;
  float4 a = *(const float4*)row;
  float4 bq = *(const float4*)(row + 4);
  float sm = a.x + a.y + a.z + a.w + bq.x + bq.y + bq.z + bq.w;
  float ss = a.x * a.x + a.y * a.y + a.z * a.z + a.w * a.w +
             bq.x * bq.x + bq.y * bq.y + bq.z * bq.z + bq.w * bq.w;
  sm = waveSum(sm);
  ss = waveSum(ss);
  if (lane == 0) {
    float mu = sm * (1.f / CC);
    float var = ss * (1.f / CC) - mu * mu;
    muG[tokG] = mu;
    rsG[tokG] = rsqrtf(var + 1e-5f);
  }
}

// ---------------- s_load helpers ----------------
typedef __attribute__((ext_vector_type(8))) float f32x8;
typedef __attribute__((ext_vector_type(16))) float f32x16;

#define SL8(dst, off_lit) \
  asm volatile("s_load_dwordx8 %0, %1, " off_lit : "=s"(dst) : "s"(bp))

#define SL16(dst, off_lit) \
  asm volatile("s_load_dwordx16 %0, %1, " off_lit : "=s"(dst) : "s"(bp))

#define SWAIT8() \
  asm volatile("s_waitcnt lgkmcnt(0)" \
               : "+s"(s0), "+s"(s1), "+s"(s2), "+s"(s3), \
                 "+s"(s4), "+s"(s5), "+s"(s6), "+s"(s7))

#define SWAIT5() \
  asm volatile("s_waitcnt lgkmcnt(0)" \
               : "+s"(s0), "+s"(s1), "+s"(s2), "+s"(s3), "+s"(s4))

#define SWAITQ() \
  asm volatile("s_waitcnt lgkmcnt(0)" : "+s"(q0), "+s"(q1), "+s"(q2), "+s"(q3))

#define SWAITP() \
  asm volatile("s_waitcnt lgkmcnt(0)" \
               : "+s"(q0), "+s"(q1), "+s"(q2), "+s"(q3), "+s"(q4))

#define DOT8(S, I) do { float t_ = acc[I]; \
  t_ = fmaf(S[0], a[0], t_); t_ = fmaf(S[1], a[1], t_); \
  t_ = fmaf(S[2], a[2], t_); t_ = fmaf(S[3], a[3], t_); \
  t_ = fmaf(S[4], a[4], t_); t_ = fmaf(S[5], a[5], t_); \
  t_ = fmaf(S[6], a[6], t_); t_ = fmaf(S[7], a[7], t_); \
  acc[I] = t_; } while (0)

#define DOT16(S, I) do { float t_ = acc[I]; \
  t_ = fmaf(S[0], a[0], t_);   t_ = fmaf(S[1], a[1], t_); \
  t_ = fmaf(S[2], a[2], t_);   t_ = fmaf(S[3], a[3], t_); \
  t_ = fmaf(S[4], a[4], t_);   t_ = fmaf(S[5], a[5], t_); \
  t_ = fmaf(S[6], a[6], t_);   t_ = fmaf(S[7], a[7], t_); \
  t_ = fmaf(S[8], a[8], t_);   t_ = fmaf(S[9], a[9], t_); \
  t_ = fmaf(S[10], a[10], t_); t_ = fmaf(S[11], a[11], t_); \
  t_ = fmaf(S[12], a[12], t_); t_ = fmaf(S[13], a[13], t_); \
  t_ = fmaf(S[14], a[14], t_); t_ = fmaf(S[15], a[15], t_); \
  acc[I] = t_; } while (0)

// Empty volatile asm: pins loaded floats into registers exactly once.
#define PIN16(a0, a1, a2, a3) \
  asm volatile("" : "+v"(a0.x), "+v"(a0.y), "+v"(a0.z), "+v"(a0.w), \
                    "+v"(a1.x), "+v"(a1.y), "+v"(a1.z), "+v"(a1.w), \
                    "+v"(a2.x), "+v"(a2.y), "+v"(a2.z), "+v"(a2.w), \
                    "+v"(a3.x), "+v"(a3.y), "+v"(a3.z), "+v"(a3.w))

// ---------------- fused x@w1g (+gelu) @ w2 per 64-token tile --------------
__global__ __launch_bounds__(512, 2) void k_gemm(const float* __restrict__ img,
                                                 const float* __restrict__ w1gT,
                                                 const float* __restrict__ A,
                                                 const float* __restrict__ Bc,
                                                 const float* __restrict__ muG,
                                                 const float* __restrict__ rsG,
                                                 const float* __restrict__ w2,
                                                 const float* __restrict__ b2,
                                                 float* __restrict__ y) {
  __shared__ float hL[64 * 105];
  __shared__ float w2L[HID * 40];
  int t = threadIdx.x;
  int tok = t & 63, wv = t >> 6;
  int tokG = blockIdx.x * 64 + tok;
  int b = tokG / NN, n = tokG - b * NN;
  const float* xrow = img + ((size_t)b * 197 + 1 + n) * CC;

  for (int p = t; p < HID * 40; p += 512) {
    int j = p / 40, k = p - j * 40;
    w2L[p] = (k < KEEPN) ? w2[(size_t)j * KEEPN + k] : 0.f;
  }

  int jbase = wv * 13;
  uint64_t a64 = (uint64_t)(w1gT + (size_t)jbase * 512);
  uint32_t alo = __builtin_amdgcn_readfirstlane((uint32_t)a64);
  uint32_t ahi = __builtin_amdgcn_readfirstlane((uint32_t)(a64 >> 32));
  uint64_t sbase = ((uint64_t)ahi << 32) | alo;

  float acc[13];
#pragma unroll
  for (int i = 0; i < 13; ++i) acc[i] = 0.f;

  float4 c0 = *(const float4*)(xrow);
  float4 c1 = *(const float4*)(xrow + 4);
  for (int k0 = 0; k0 < CC; k0 += 8) {
    float4 nx0, nx1;
    if (k0 + 8 < CC) {
      nx0 = *(const float4*)(xrow + k0 + 8);
      nx1 = *(const float4*)(xrow + k0 + 12);
    } else {
      nx0 = c0; nx1 = c1;
    }
    float a[8] = {c0.x, c0.y, c0.z, c0.w, c1.x, c1.y, c1.z, c1.w};
    const uint64_t bp = sbase + (uint64_t)k0 * 4;
    f32x8 s0, s1, s2, s3, s4, s5, s6, s7;
    SL8(s0, "0x0");    SL8(s1, "0x800");  SL8(s2, "0x1000"); SL8(s3, "0x1800");
    SL8(s4, "0x2000"); SL8(s5, "0x2800"); SL8(s6, "0x3000"); SL8(s7, "0x3800");
    SWAIT8();
    DOT8(s0, 0); DOT8(s1, 1); DOT8(s2, 2); DOT8(s3, 3);
    DOT8(s4, 4); DOT8(s5, 5); DOT8(s6, 6); DOT8(s7, 7);
    SL8(s0, "0x4000"); SL8(s1, "0x4800"); SL8(s2, "0x5000"); SL8(s3, "0x5800");
    SL8(s4, "0x6000");
    SWAIT5();
    DOT8(s0, 8); DOT8(s1, 9); DOT8(s2, 10); DOT8(s3, 11); DOT8(s4, 12);
    c0 = nx0; c1 = nx1;
  }

  float mu = muG[tokG], rsg = rsG[tokG];
  float nmr = -rsg * mu;
#pragma unroll
  for (int i = 0; i < 13; ++i) {
    int j = jbase + i;
    float h = fmaf(rsg, acc[i], fmaf(nmr, A[j], Bc[j]));
    hL[tok * 105 + j] = 0.5f * h * (1.f + erff(h * 0.70710678118654752f));
  }
  __syncthreads();

  int kg = wv;
  float acc2[5];
#pragma unroll
  for (int i = 0; i < 5; ++i) {
    int k = kg * 5 + i;
    acc2[i] = (k < KEEPN) ? b2[k] : 0.f;
  }
  for (int j = 0; j < HID; ++j) {
    float hv = hL[tok * 105 + j];
#pragma unroll
    for (int i = 0; i < 5; ++i) {
      int k = kg * 5 + i;
      if (k < KEEPN) acc2[i] = fmaf(hv, w2L[j * 40 + k], acc2[i]);
    }
  }
#pragma unroll
  for (int i = 0; i < 5; ++i) {
    int k = kg * 5 + i;
    if (k < KEEPN) y[(size_t)tokG * 40 + k] = acc2[i];
  }
}

// ---------------- score kernel (R12-proven config: (256,4)) --------------
__global__ __launch_bounds__(256, 4) void k_score(const float* __restrict__ img,
                                                  const float* __restrict__ cap,
                                                  const float* __restrict__ cinvG,
                                                  const float* __restrict__ ninvG,
                                                  const float* __restrict__ s_imG,
                                                  float* __restrict__ scoreG,
                                                  float* __restrict__ S_T) {
  int j = blockIdx.x;
  int gi = blockIdx.y * 256 + threadIdx.x;
  if (gi >= 48 * 197) return;
  int b = gi / 197;
  int tok = gi - b * 197;
  int blk = b * B_T + j;

  const float* capj = cap + (size_t)j * MQ * CC;
  const float* spn = img + (size_t)gi * CC;  // == (b*197+tok)*CC

  float acc[MQ];
#pragma unroll
  for (int m = 0; m < MQ; ++m) acc[m] = 0.f;

  for (int k0 = 0; k0 < CC; k0 += 16) {
    float4 a0 = *(const float4*)(spn + k0);
    float4 a1 = *(const float4*)(spn + k0 + 4);
    float4 a2 = *(const float4*)(spn + k0 + 8);
    float4 a3 = *(const float4*)(spn + k0 + 12);
    PIN16(a0, a1, a2, a3);  // materialize the row chunk exactly once
    float a[16] = {a0.x, a0.y, a0.z, a0.w, a1.x, a1.y, a1.z, a1.w,
                   a2.x, a2.y, a2.z, a2.w, a3.x, a3.y, a3.z, a3.w};
    const float* bp = capj + k0;
    f32x16 q0, q1, q2, q3;
    SL16(q0, "0x0");    SL16(q1, "0x800");  SL16(q2, "0x1000"); SL16(q3, "0x1800");
    SWAITQ();
    DOT16(q0, 0); DOT16(q1, 1); DOT16(q2, 2); DOT16(q3, 3);
    SL16(q0, "0x2000"); SL16(q1, "0x2800"); SL16(q2, "0x3000"); SL16(q3, "0x3800");
    SWAITQ();
    DOT16(q0, 4); DOT16(q1, 5); DOT16(q2, 6); DOT16(q3, 7);
    SL16(q0, "0x4000"); SL16(q1, "0x4800"); SL16(q2, "0x5000"); SL16(q3, "0x5800");
    SWAITQ();
    DOT16(q0, 8); DOT16(q1, 9); DOT16(q2, 10); DOT16(q3, 11);
    SL16(q0, "0x6000"); SL16(q1, "0x6800"); SL16(q2, "0x7000"); SL16(q3, "0x7800");
    SWAITQ();
    DOT16(q0, 12); DOT16(q1, 13); DOT16(q2, 14); DOT16(q3, 15);
    SL16(q0, "0x8000"); SL16(q1, "0x8800"); SL16(q2, "0x9000"); SL16(q3, "0x9800");
    SWAITQ();
    DOT16(q0, 16); DOT16(q1, 17); DOT16(q2, 18); DOT16(q3, 19);
    SL16(q0, "0xA000"); SL16(q1, "0xA800"); SL16(q2, "0xB000"); SL16(q3, "0xB800");
    SWAITQ();
    DOT16(q0, 20); DOT16(q1, 21); DOT16(q2, 22); DOT16(q3, 23);
    SL16(q0, "0xC000"); SL16(q1, "0xC800"); SL16(q2, "0xD000"); SL16(q3, "0xD800");
    SWAITQ();
    DOT16(q0, 24); DOT16(q1, 25); DOT16(q2, 26); DOT16(q3, 27);
    SL16(q0, "0xE000"); SL16(q1, "0xE800"); SL16(q2, "0xF000"); SL16(q3, "0xF800");
    SWAITQ();
    DOT16(q0, 28); DOT16(q1, 29); DOT16(q2, 30); DOT16(q3, 31);
  }

  float* st = S_T + ((size_t)blk * 197 + tok) * 32;
#pragma unroll
  for (int g = 0; g < 8; ++g) {
    float4 v;
    v.x = acc[g * 4 + 0]; v.y = acc[g * 4 + 1];
    v.z = acc[g * 4 + 2]; v.w = acc[g * 4 + 3];
    *(float4*)(st + g * 4) = v;
  }

  if (tok >= 1) {
    int n = tok - 1;
    float attn = -INFINITY;
#pragma unroll
    for (int m = 0; m < MQ; ++m) attn = fmaxf(attn, acc[m] * cinvG[j * MQ + m]);
    scoreG[(size_t)blk * NN + n] = s_imG[b * NN + n] + attn * ninvG[b * NN + n];
  }
}

// ---------------- partition + softmaxes -> global (small) -----------------
__global__ __launch_bounds__(256, 4) void k_part(const float* __restrict__ scoreG,
                                                 const float* __restrict__ yG,
                                                 const float* __restrict__ scaleG,
                                                 int* __restrict__ keepIG,
                                                 int* __restrict__ nonIG,
                                                 float* __restrict__ nonWG,
                                                 float* __restrict__ wGo) {
  int blk = blockIdx.x;
  int b = blk / B_T;
  int t = threadIdx.x;

  __shared__ float scoreL[NN];
  __shared__ int keepI[NKEEP];
  __shared__ int nonI[NKEEP];
  __shared__ float nonSc[NKEEP];
  __shared__ float yL[NKEEP * 40];
  __shared__ float sc0, sc1;

  if (t < NN) scoreL[t] = scoreG[(size_t)blk * NN + t];
  __syncthreads();

  if (t < NN) {  // exact stable-descending rank
    float ms = scoreL[t];
    int rank = 0;
    for (int q = 0; q < NN; ++q) {
      float sq = scoreL[q];
      rank += (sq > ms) || (sq == ms && q < t);
    }
    if (rank < NKEEP) keepI[rank] = t;
    else { nonI[rank - NKEEP] = t; nonSc[rank - NKEEP] = ms; }
  }
  __syncthreads();

  float scaleV = scaleG[0];
  for (int p = t; p < NKEEP * 40; p += 256) {
    int i = p / 40, k = p - i * 40;
    yL[p] = (k < KEEPN) ? yG[(size_t)(b * NN + keepI[i]) * 40 + k] : 0.f;
  }
  if (t < 64) {
    float v0 = nonSc[t];
    float v1 = (t + 64 < NKEEP) ? nonSc[t + 64] : -INFINITY;
    float mx = waveMax(fmaxf(v0, v1));
    float e = expf(v0 - mx) + ((t + 64 < NKEEP) ? expf(v1 - mx) : 0.f);
    float s = waveSum(e);
    if (t == 0) { sc0 = mx; sc1 = s; }
  }
  __syncthreads();
  if (t < NKEEP) {
    nonWG[(size_t)blk * NKEEP + t] = expf(nonSc[t] - sc0) / sc1;
    keepIG[(size_t)blk * NKEEP + t] = keepI[t];
    nonIG[(size_t)blk * NKEEP + t] = nonI[t];
  }
  if (t >= 128 && t < 128 + KEEPN) {  // softmax over i per k
    int k = t - 128;
    float mx = -INFINITY;
    for (int i = 0; i < NKEEP; ++i) mx = fmaxf(mx, yL[i * 40 + k] * scaleV);
    float s = 0.f;
    for (int i = 0; i < NKEEP; ++i) {
      float e = expf(yL[i * 40 + k] * scaleV - mx);
      yL[i * 40 + k] = e;
      s += e;
    }
    float rs = 1.f / s;
    for (int i = 0; i < NKEEP; ++i) yL[i * 40 + k] *= rs;
  }
  __syncthreads();
  for (int p = t; p < NKEEP * 40; p += 256)
    wGo[(size_t)blk * (NKEEP * 40) + p] = yL[p];
}

// ---------------- main: thread-owns-channel aggr + S-fed c2t --------------
// phase A: 2 keep-rows per SMEM wait (rows i,i+1 contiguous in wG -> 5xSL16,
// one lgkmcnt(0) drain per 160 cyc of FMA instead of per 80).
__global__ __launch_bounds__(512, 4) void k_main4(const float* __restrict__ img,
                                                  const float* __restrict__ S_T,
                                                  const int* __restrict__ keepIG,
                                                  const int* __restrict__ nonIG,
                                                  const float* __restrict__ nonWG,
                                                  const float* __restrict__ wG,
                                                  const float* __restrict__ cinvG,
                                                  const float* __restrict__ clsInvG,
                                                  float* __restrict__ out) {
  int blk = blockIdx.x;
  int b = blk / B_T, j = blk - b * B_T;
  int t = threadIdx.x, lane = t & 63, wv = t >> 6;

  __shared__ float wL[NKEEP * 40];   // 15.7 KB
  __shared__ int keepL[NKEEP];
  __shared__ int nonL[NKEEP];
  __shared__ float nonWL[NKEEP];
  __shared__ float cinvL[32];
  __shared__ float red8[40][8];
  __shared__ float aggrInvL[40];
  __shared__ float extRed[8];
  __shared__ float c2tL[TOKS * 33];
  __shared__ float rowM[MQ], colM[TOKS];
  __shared__ float extInvS;

  for (int p = t; p < NKEEP * 40; p += 512)
    wL[p] = wG[(size_t)blk * (NKEEP * 40) + p];
  if (t < NKEEP) {
    keepL[t] = keepIG[(size_t)blk * NKEEP + t];
    nonL[t] = nonIG[(size_t)blk * NKEEP + t];
    nonWL[t] = nonWG[(size_t)blk * NKEEP + t];
  }
  if (t >= 128 && t < 160) cinvL[t - 128] = cinvG[j * MQ + (t - 128)];
  __syncthreads();

  const float* imgsp = img + ((size_t)b * 197 + 1) * CC;

  // ---- phase A: thread owns channel c=t; aggr[c][k] for all 40 k ----
  float acc[40];
#pragma unroll
  for (int k = 0; k < 40; ++k) acc[k] = 0.f;
  {
    const float* wp = wG + (size_t)blk * (NKEEP * 40);
    for (int ii = 0; ii < 49; ++ii) {  // 2 rows per iteration, 98 = 49*2
      int r0 = keepL[2 * ii], r1 = keepL[2 * ii + 1];
      float xv0 = imgsp[(size_t)r0 * CC + t];  // coalesced per-lane
      float xv1 = imgsp[(size_t)r1 * CC + t];
      const float* bp = wp + (size_t)(2 * ii) * 40;  // rows 2ii,2ii+1: 80 floats
      f32x16 q0, q1, q2, q3, q4;
      SL16(q0, "0x0");  SL16(q1, "0x40"); SL16(q2, "0x80");
      SL16(q3, "0xC0"); SL16(q4, "0x100");
      SWAITP();
      // row r0: floats [0,40) = q0[0..15], q1[0..15], q2[0..7]
#pragma unroll
      for (int q = 0; q < 16; ++q) acc[q] = fmaf(q0[q], xv0, acc[q]);
#pragma unroll
      for (int q = 0; q < 16; ++q) acc[16 + q] = fmaf(q1[q], xv0, acc[16 + q]);
#pragma unroll
      for (int q = 0; q < 8; ++q) acc[32 + q] = fmaf(q2[q], xv0, acc[32 + q]);
      // row r1: floats [40,80) = q2[8..15], q3[0..15], q4[0..15]
#pragma unroll
      for (int q = 0; q < 8; ++q) acc[q] = fmaf(q2[8 + q], xv1, acc[q]);
#pragma unroll
      for (int q = 0; q < 16; ++q) acc[8 + q] = fmaf(q3[q], xv1, acc[8 + q]);
#pragma unroll
      for (int q = 0; q < 16; ++q) acc[24 + q] = fmaf(q4[q], xv1, acc[24 + q]);
    }
  }
#pragma unroll
  for (int k = 0; k < 40; ++k) {
    float ss = waveSum(acc[k] * acc[k]);
    if (lane == 0) red8[k][wv] = ss;
  }

  // ---- phase A2: extra token (thread owns channel) ----
  float ev = 0.f;
  for (int i = 0; i < NKEEP; ++i)
    ev = fmaf(nonWL[i], imgsp[(size_t)nonL[i] * CC + t], ev);
  {
    float ss = waveSum(ev * ev);
    if (lane == 0) extRed[wv] = ss;
  }
  __syncthreads();
  if (t < 40) {
    float s = 0.f;
#pragma unroll
    for (int q = 0; q < 8; ++q) s += red8[t][q];
    aggrInvL[t] = 1.f / fmaxf(sqrtf(s), 1e-12f);
  }
  if (t == 64) {
    float s = 0.f;
#pragma unroll
    for (int q = 0; q < 8; ++q) s += extRed[q];
    extInvS = 1.f / fmaxf(sqrtf(s), 1e-12f);
  }
  __syncthreads();

  // ---- phase B: c2t columns from S_T; half-wave s owns 3 k's ----
  {
    int m = t & 31;
    int s = t >> 5;  // 0..15
    const float* stb = S_T + ((size_t)blk * 197 + 1) * 32 + m;
    if (s < 13) {
      int k0 = s * 3;  // 13*3 = 39 k's exactly
      float a0 = 0.f, a1 = 0.f, a2 = 0.f;
      for (int i = 0; i < NKEEP; ++i) {
        float sv = stb[(size_t)keepL[i] * 32];
        const float* wr = wL + i * 40 + k0;
        a0 = fmaf(wr[0], sv, a0);
        a1 = fmaf(wr[1], sv, a1);
        a2 = fmaf(wr[2], sv, a2);
      }
      float cm = cinvL[m];
      c2tL[(1 + k0) * 33 + m] = a0 * cm * aggrInvL[k0];
      c2tL[(2 + k0) * 33 + m] = a1 * cm * aggrInvL[k0 + 1];
      c2tL[(3 + k0) * 33 + m] = a2 * cm * aggrInvL[k0 + 2];
    } else if (s == 13) {  // extra column
      float ec = 0.f;
      for (int i = 0; i < NKEEP; ++i)
        ec = fmaf(nonWL[i], stb[(size_t)nonL[i] * 32], ec);
      c2tL[40 * 33 + m] = ec * cinvL[m] * extInvS;
    } else if (s == 14) {  // cls column
      float cv = S_T[((size_t)blk * 197) * 32 + m];
      c2tL[0 * 33 + m] = cv * cinvL[m] * clsInvG[b];
    }
  }
  __syncthreads();

  // ---- phase C: leaky + row/col means ----
  if (t < MQ) {
    float mx = -INFINITY;
    for (int tt = 0; tt < TOKS; ++tt) mx = fmaxf(mx, c2tL[tt * 33 + t]);
    rowM[t] = (mx >= 0.f) ? mx : 0.1f * mx;
  } else if (t >= 64 && t < 64 + TOKS) {
    int tt = t - 64;
    float mx = -INFINITY;
    for (int m = 0; m < MQ; ++m) mx = fmaxf(mx, c2tL[tt * 33 + m]);
    colM[tt] = (mx >= 0.f) ? mx : 0.1f * mx;
  }
  __syncthreads();
  if (t == 0) {
    float r = 0.f, c = 0.f;
    for (int m = 0; m < MQ; ++m) r += rowM[m];
    for (int tt = 0; tt < TOKS; ++tt) c += colM[tt];
    out[b * B_T + j] = r * (1.f / MQ) + c * (1.f / TOKS);
  }
}

extern "C" void kernel_launch(void* const* d_in, const int* in_sizes, int n_in,
                              void* d_out, int out_size, void* d_ws, size_t ws_size,
                              hipStream_t stream) {
  const float* img = (const float*)d_in[0];
  const float* cap = (const float*)d_in[1];
  const float* ln_g = (const float*)d_in[3];
  const float* ln_b = (const float*)d_in[4];
  const float* w1 = (const float*)d_in[5];
  const float* b1 = (const float*)d_in[6];
  const float* w2 = (const float*)d_in[7];
  const float* b2 = (const float*)d_in[8];
  const float* scale = (const float*)d_in[9];
  float* ws = (float*)d_ws;
  float* cinv   = ws;                 // 1536
  float* ninv   = ws + 1536;          // 9408
  float* s_im   = ws + 10944;         // 9408
  float* clsi   = ws + 20352;         // 48
  float* y      = ws + 20400;         // 376320
  float* scoreW = ws + 396720;        // 451584  (overlay: mu/rs/w1gT/A/Bc)
  int*   keepIG = (int*)(ws + 848304);    // 225792
  int*   nonIG  = (int*)(ws + 1074096);   // 225792
  float* nonWG  = ws + 1299888;       // 225792
  float* wGp    = ws + 1525680;       // 9031680 (2304*98*40)
  float* S_T    = ws + 10557360;      // 14524416 (2304*197*32)
  float* muW  = scoreW;               // 9408
  float* rsW  = scoreW + 9408;        // 9408
  float* w1gT = scoreW + 18816;       // 53248
  float* A    = scoreW + 72064;       // 104
  float* Bc   = scoreW + 72168;       // 104
  float* out = (float*)d_out;

  k_prep_img<<<B_V, 256, 0, stream>>>(img, ninv, s_im, clsi);
  k_prep_cap<<<B_T, 256, 0, stream>>>(cap, cinv);
  k_fold<<<104, 256, 0, stream>>>(w1, b1, ln_g, ln_b, w1gT, A, Bc);
  k_ln<<<2352, 256, 0, stream>>>(img, muW, rsW);
  k_gemm<<<147, 512, 0, stream>>>(img, w1gT, A, Bc, muW, rsW, w2, b2, y);
  {
    dim3 g(48, 37);
    k_score<<<g, 256, 0, stream>>>(img, cap, cinv, ninv, s_im, scoreW, S_T);
  }
  k_part<<<B_V * B_T, 256, 0, stream>>>(scoreW, y, scale, keepIG, nonIG, nonWG, wGp);
  k_main4<<<B_V * B_T, 512, 0, stream>>>(img, S_T, keepIG, nonIG, nonWG, wGp, cinv,
                                         clsi, out);
}